// Round 1
// baseline (164.599 us; speedup 1.0000x reference)
//
#include <hip/hip_runtime.h>
#include <hip/hip_bf16.h>

#define BATCH 4096
#define IN_DIM 3072
#define HID 1024
#define NSTEP 12

typedef __attribute__((ext_vector_type(8))) short short8;
typedef __attribute__((ext_vector_type(4))) float f32x4;
typedef __attribute__((ext_vector_type(4))) unsigned short ushort4v;

__device__ __forceinline__ void gload_lds16(const void* g, void* lds) {
  __builtin_amdgcn_global_load_lds(
      (const __attribute__((address_space(1))) void*)g,
      (__attribute__((address_space(3))) void*)lds, 16, 0, 0);
}

__device__ __forceinline__ unsigned short f32_to_bf16(float f) {
  unsigned int u = __builtin_bit_cast(unsigned int, f);
  unsigned int r = u + 0x7fffu + ((u >> 16) & 1u);
  return (unsigned short)(r >> 16);
}

// f32 -> bf16 conversion, float4 loads
__global__ void cvt_kernel(const float* __restrict__ src,
                           unsigned short* __restrict__ dst, int n4) {
  int stride = gridDim.x * blockDim.x;
  for (int i = blockIdx.x * blockDim.x + threadIdx.x; i < n4; i += stride) {
    const float4 v = reinterpret_cast<const float4*>(src)[i];
    ushort4v o;
    o.x = f32_to_bf16(v.x);
    o.y = f32_to_bf16(v.y);
    o.z = f32_to_bf16(v.z);
    o.w = f32_to_bf16(v.w);
    reinterpret_cast<ushort4v*>(dst)[i] = o;
  }
}

// NT GEMM: C[M,N] = A[M,K] * B[N,K]^T + bias, 128x128 tile, BK=32, 4 waves.
// EPI=0: RK4 ODE epilogue -> f32 hidden (Cout) + bf16 hidden (Hb)
// EPI=1: sigmoid epilogue -> f32 out (Cout)
template <int EPI>
__global__ __launch_bounds__(256) void gemm_nt(
    const unsigned short* __restrict__ A, const unsigned short* __restrict__ B,
    const float* __restrict__ bias, float* __restrict__ Cout,
    unsigned short* __restrict__ Hb, int M, int N, int K) {
  __shared__ unsigned short As[128 * 32];
  __shared__ unsigned short Bs[128 * 32];

  const int tid = threadIdx.x;
  const int wave = tid >> 6;
  const int lane = tid & 63;
  const int wrow = wave >> 1, wcol = wave & 1;
  const int bm = blockIdx.x, bn = blockIdx.y;

  const unsigned short* Ablk = A + (size_t)bm * 128 * K;
  const unsigned short* Bblk = B + (size_t)bn * 128 * K;

  // staging: chunk c = 16 rows x 32 cols = 1KB; lane l -> row l/4, col (l&3)*8
  const int srow = lane >> 2;
  const int scol = (lane & 3) * 8;

  f32x4 acc[4][4] = {};

  for (int k0 = 0; k0 < K; k0 += 32) {
#pragma unroll
    for (int i = 0; i < 2; ++i) {
      int c = wave * 2 + i;
      gload_lds16(Ablk + (size_t)(c * 16 + srow) * K + (k0 + scol),
                  (void*)&As[c * 512]);
      gload_lds16(Bblk + (size_t)(c * 16 + srow) * K + (k0 + scol),
                  (void*)&Bs[c * 512]);
    }
    __syncthreads();

    const int fr = lane & 15;
    const int fk = (lane >> 4) * 8;
    short8 af[4], bfr[4];
#pragma unroll
    for (int m = 0; m < 4; ++m)
      af[m] = *reinterpret_cast<const short8*>(
          &As[(wrow * 64 + m * 16 + fr) * 32 + fk]);
#pragma unroll
    for (int n = 0; n < 4; ++n)
      bfr[n] = *reinterpret_cast<const short8*>(
          &Bs[(wcol * 64 + n * 16 + fr) * 32 + fk]);
#pragma unroll
    for (int m = 0; m < 4; ++m)
#pragma unroll
      for (int n = 0; n < 4; ++n)
        acc[m][n] = __builtin_amdgcn_mfma_f32_16x16x32_bf16(af[m], bfr[n],
                                                            acc[m][n], 0, 0, 0);
    __syncthreads();
  }

  // epilogue: C/D layout col=lane&15, row=(lane>>4)*4+reg (m89-verified)
  const int fr = lane & 15;
  const int rquad = (lane >> 4) * 4;
  const int colbase = bn * 128 + wcol * 64 + fr;
  const int rowbase = bm * 128 + wrow * 64 + rquad;

  float bias_v[4];
#pragma unroll
  for (int n = 0; n < 4; ++n) bias_v[n] = bias[colbase + n * 16];

  if (EPI == 0) {
    const float dt = 1.0f / (float)NSTEP;
    const float h2 = 0.5f * dt, hd = dt, h6 = dt / 6.0f;
#pragma unroll
    for (int m = 0; m < 4; ++m) {
#pragma unroll
      for (int h = 0; h < 2; ++h) {
        float g[8], y[8];
#pragma unroll
        for (int e = 0; e < 8; ++e) {
          int n = h * 2 + (e >> 2), r = e & 3;
          g[e] = acc[m][n][r] + bias_v[n];
          y[e] = 0.0f;
        }
#pragma unroll 1
        for (int s = 0; s < NSTEP; ++s) {
          float k1[8], k2[8], k3[8], k4[8];
#pragma unroll
          for (int e = 0; e < 8; ++e) {
            float t = __sinf(y[e] + g[e]);
            k1[e] = t * t - y[e];
          }
#pragma unroll
          for (int e = 0; e < 8; ++e) {
            float yy = fmaf(h2, k1[e], y[e]);
            float t = __sinf(yy + g[e]);
            k2[e] = t * t - yy;
          }
#pragma unroll
          for (int e = 0; e < 8; ++e) {
            float yy = fmaf(h2, k2[e], y[e]);
            float t = __sinf(yy + g[e]);
            k3[e] = t * t - yy;
          }
#pragma unroll
          for (int e = 0; e < 8; ++e) {
            float yy = fmaf(hd, k3[e], y[e]);
            float t = __sinf(yy + g[e]);
            k4[e] = t * t - yy;
          }
#pragma unroll
          for (int e = 0; e < 8; ++e) {
            float ks = k1[e] + 2.0f * (k2[e] + k3[e]) + k4[e];
            y[e] = fmaf(h6, ks, y[e]);
          }
        }
#pragma unroll
        for (int e = 0; e < 8; ++e) {
          int n = h * 2 + (e >> 2), r = e & 3;
          size_t idx = (size_t)(rowbase + m * 16 + r) * N + (colbase + n * 16);
          Cout[idx] = y[e];
          Hb[idx] = f32_to_bf16(y[e]);
        }
      }
    }
  } else {
#pragma unroll
    for (int m = 0; m < 4; ++m)
#pragma unroll
      for (int n = 0; n < 4; ++n)
#pragma unroll
        for (int r = 0; r < 4; ++r) {
          float v = acc[m][n][r] + bias_v[n];
          float o = 1.0f / (1.0f + __expf(-v));
          size_t idx = (size_t)(rowbase + m * 16 + r) * N + (colbase + n * 16);
          Cout[idx] = o;
        }
  }
}

extern "C" void kernel_launch(void* const* d_in, const int* in_sizes, int n_in,
                              void* d_out, int out_size, void* d_ws,
                              size_t ws_size, hipStream_t stream) {
  const float* x = (const float*)d_in[0];
  const float* We = (const float*)d_in[1];
  const float* be = (const float*)d_in[2];
  const float* Wd = (const float*)d_in[3];
  const float* bd = (const float*)d_in[4];

  float* out = (float*)d_out;                       // [4096,3072]
  float* hid = out + (size_t)BATCH * IN_DIM;        // [4096,1024]

  unsigned short* xb = (unsigned short*)d_ws;       // bf16 x   [4096,3072]
  unsigned short* Web = xb + (size_t)BATCH * IN_DIM;   // bf16 We  [1024,3072]
  unsigned short* Wdb = Web + (size_t)HID * IN_DIM;    // bf16 Wd  [3072,1024]
  unsigned short* hb = Wdb + (size_t)IN_DIM * HID;     // bf16 hid [4096,1024]

  cvt_kernel<<<2048, 256, 0, stream>>>(x, xb, BATCH * IN_DIM / 4);
  cvt_kernel<<<1024, 256, 0, stream>>>(We, Web, HID * IN_DIM / 4);
  cvt_kernel<<<1024, 256, 0, stream>>>(Wd, Wdb, IN_DIM * HID / 4);

  dim3 g1(BATCH / 128, HID / 128);
  gemm_nt<0><<<g1, 256, 0, stream>>>(xb, Web, be, hid, hb, BATCH, HID, IN_DIM);

  dim3 g2(BATCH / 128, IN_DIM / 128);
  gemm_nt<1><<<g2, 256, 0, stream>>>(hb, Wdb, bd, out, nullptr, BATCH, IN_DIM,
                                     HID);
}

// Round 2
// 142.540 us; speedup vs baseline: 1.1548x; 1.1548x over previous
//
#include <hip/hip_runtime.h>
#include <hip/hip_bf16.h>

#define BATCH 4096
#define IN_DIM 3072
#define HID 1024
#define NSTEP 12

typedef __attribute__((ext_vector_type(8))) short short8;
typedef __attribute__((ext_vector_type(4))) float f32x4;
typedef __attribute__((ext_vector_type(4))) unsigned short ushort4v;

__device__ __forceinline__ void gload_lds16(const void* g, void* lds) {
  __builtin_amdgcn_global_load_lds(
      (const __attribute__((address_space(1))) void*)g,
      (__attribute__((address_space(3))) void*)lds, 16, 0, 0);
}

__device__ __forceinline__ unsigned short f32_to_bf16(float f) {
  unsigned int u = __builtin_bit_cast(unsigned int, f);
  unsigned int r = u + 0x7fffu + ((u >> 16) & 1u);
  return (unsigned short)(r >> 16);
}

// f32 -> bf16 conversion, float4 loads
__global__ void cvt_kernel(const float* __restrict__ src,
                           unsigned short* __restrict__ dst, int n4) {
  int stride = gridDim.x * blockDim.x;
  for (int i = blockIdx.x * blockDim.x + threadIdx.x; i < n4; i += stride) {
    const float4 v = reinterpret_cast<const float4*>(src)[i];
    ushort4v o;
    o.x = f32_to_bf16(v.x);
    o.y = f32_to_bf16(v.y);
    o.z = f32_to_bf16(v.z);
    o.w = f32_to_bf16(v.w);
    reinterpret_cast<ushort4v*>(dst)[i] = o;
  }
}

// RK4 nmODE integrator, elementwise, full occupancy. Reads gamma (f32),
// writes y(1) f32 in-place over gamma, plus bf16 copy for GEMM2.
__global__ __launch_bounds__(256) void ode_kernel(const float* gamma,
                                                  float* hid,
                                                  unsigned short* __restrict__ hb,
                                                  int n4) {
  const float dt = 1.0f / (float)NSTEP;
  const float h2 = 0.5f * dt, hd = dt, h6 = dt / 6.0f;
  int stride = gridDim.x * blockDim.x;
  for (int i = blockIdx.x * blockDim.x + threadIdx.x; i < n4; i += stride) {
    const float4 g4 = reinterpret_cast<const float4*>(gamma)[i];
    float g[4] = {g4.x, g4.y, g4.z, g4.w};
    float y[4] = {0.0f, 0.0f, 0.0f, 0.0f};
#pragma unroll 1
    for (int s = 0; s < NSTEP; ++s) {
      float k1[4], k2[4], k3[4], k4[4];
#pragma unroll
      for (int e = 0; e < 4; ++e) {
        float t = __sinf(y[e] + g[e]);
        k1[e] = t * t - y[e];
      }
#pragma unroll
      for (int e = 0; e < 4; ++e) {
        float yy = fmaf(h2, k1[e], y[e]);
        float t = __sinf(yy + g[e]);
        k2[e] = t * t - yy;
      }
#pragma unroll
      for (int e = 0; e < 4; ++e) {
        float yy = fmaf(h2, k2[e], y[e]);
        float t = __sinf(yy + g[e]);
        k3[e] = t * t - yy;
      }
#pragma unroll
      for (int e = 0; e < 4; ++e) {
        float yy = fmaf(hd, k3[e], y[e]);
        float t = __sinf(yy + g[e]);
        k4[e] = t * t - yy;
      }
#pragma unroll
      for (int e = 0; e < 4; ++e) {
        float ks = k1[e] + 2.0f * (k2[e] + k3[e]) + k4[e];
        y[e] = fmaf(h6, ks, y[e]);
      }
    }
    float4 o4;
    o4.x = y[0]; o4.y = y[1]; o4.z = y[2]; o4.w = y[3];
    reinterpret_cast<float4*>(hid)[i] = o4;
    ushort4v ob;
    ob.x = f32_to_bf16(y[0]);
    ob.y = f32_to_bf16(y[1]);
    ob.z = f32_to_bf16(y[2]);
    ob.w = f32_to_bf16(y[3]);
    reinterpret_cast<ushort4v*>(hb)[i] = ob;
  }
}

// NT GEMM: C[M,N] = A[M,K] * B[N,K]^T + bias.
// BMxBN tile, BK=32, 4 waves (WM x WN), double-buffered LDS staging.
// EPI=0: plain (gamma) f32 out.  EPI=1: sigmoid f32 out.
template <int BM, int BN, int WM, int WN, int EPI>
__global__ __launch_bounds__(256) void gemm_nt(
    const unsigned short* __restrict__ A, const unsigned short* __restrict__ B,
    const float* __restrict__ bias, float* __restrict__ Cout, int M, int N,
    int K) {
  constexpr int WTM = BM / WM;          // wave tile rows
  constexpr int WTN = BN / WN;          // wave tile cols
  constexpr int AM = WTM / 16;          // acc frags m
  constexpr int AN = WTN / 16;          // acc frags n
  constexpr int CA = BM / 16;           // A chunks (16 rows x 32 cols = 1KB)
  constexpr int TC = (BM + BN) / 16;    // total chunks
  constexpr int CPW = TC / 4;           // chunks per wave

  __shared__ unsigned short As[2][BM * 32];
  __shared__ unsigned short Bs[2][BN * 32];

  const int tid = threadIdx.x;
  const int wave = tid >> 6;
  const int lane = tid & 63;
  const int wrow = wave / WN, wcol = wave % WN;
  const int bm = blockIdx.x, bn = blockIdx.y;

  const unsigned short* Ablk = A + (size_t)bm * BM * K;
  const unsigned short* Bblk = B + (size_t)bn * BN * K;

  const int srow = lane >> 2;
  const int scol = (lane & 3) * 8;

  auto STAGE = [&](int buf, int k0) {
#pragma unroll
    for (int i = 0; i < CPW; ++i) {
      int c = wave * CPW + i;
      if (c < CA) {
        gload_lds16(Ablk + (size_t)(c * 16 + srow) * K + (k0 + scol),
                    (void*)&As[buf][c * 512]);
      } else {
        int cb = c - CA;
        gload_lds16(Bblk + (size_t)(cb * 16 + srow) * K + (k0 + scol),
                    (void*)&Bs[buf][cb * 512]);
      }
    }
  };

  f32x4 acc[AM][AN] = {};
  const int fr = lane & 15;
  const int fk = (lane >> 4) * 8;

  const int nt = K / 32;
  STAGE(0, 0);
  for (int t = 0; t < nt; ++t) {
    const int buf = t & 1;
    __syncthreads();  // drains vmcnt(0): staged tile t is resident
    if (t + 1 < nt) STAGE(buf ^ 1, (t + 1) * 32);

    short8 af[AM], bfr[AN];
#pragma unroll
    for (int m = 0; m < AM; ++m)
      af[m] = *reinterpret_cast<const short8*>(
          &As[buf][(wrow * WTM + m * 16 + fr) * 32 + fk]);
#pragma unroll
    for (int n = 0; n < AN; ++n)
      bfr[n] = *reinterpret_cast<const short8*>(
          &Bs[buf][(wcol * WTN + n * 16 + fr) * 32 + fk]);
#pragma unroll
    for (int m = 0; m < AM; ++m)
#pragma unroll
      for (int n = 0; n < AN; ++n)
        acc[m][n] = __builtin_amdgcn_mfma_f32_16x16x32_bf16(af[m], bfr[n],
                                                            acc[m][n], 0, 0, 0);
  }

  // epilogue: C/D layout col=lane&15, row=(lane>>4)*4+reg (m89-verified)
  const int rquad = (lane >> 4) * 4;
  const int colbase = bn * BN + wcol * WTN + fr;
  const int rowbase = bm * BM + wrow * WTM + rquad;

#pragma unroll
  for (int n = 0; n < AN; ++n) {
    const float bv = bias[colbase + n * 16];
#pragma unroll
    for (int m = 0; m < AM; ++m)
#pragma unroll
      for (int r = 0; r < 4; ++r) {
        float v = acc[m][n][r] + bv;
        if (EPI == 1) v = 1.0f / (1.0f + __expf(-v));
        size_t idx = (size_t)(rowbase + m * 16 + r) * N + (colbase + n * 16);
        Cout[idx] = v;
      }
  }
}

extern "C" void kernel_launch(void* const* d_in, const int* in_sizes, int n_in,
                              void* d_out, int out_size, void* d_ws,
                              size_t ws_size, hipStream_t stream) {
  const float* x = (const float*)d_in[0];
  const float* We = (const float*)d_in[1];
  const float* be = (const float*)d_in[2];
  const float* Wd = (const float*)d_in[3];
  const float* bd = (const float*)d_in[4];

  float* out = (float*)d_out;                   // [4096,3072]
  float* hid = out + (size_t)BATCH * IN_DIM;    // [4096,1024] (gamma, then y)

  unsigned short* xb = (unsigned short*)d_ws;          // bf16 x   [4096,3072]
  unsigned short* Web = xb + (size_t)BATCH * IN_DIM;   // bf16 We  [1024,3072]
  unsigned short* Wdb = Web + (size_t)HID * IN_DIM;    // bf16 Wd  [3072,1024]
  unsigned short* hb = Wdb + (size_t)IN_DIM * HID;     // bf16 hid [4096,1024]

  cvt_kernel<<<2048, 256, 0, stream>>>(x, xb, BATCH * IN_DIM / 4);
  cvt_kernel<<<1024, 256, 0, stream>>>(We, Web, HID * IN_DIM / 4);
  cvt_kernel<<<1024, 256, 0, stream>>>(Wd, Wdb, IN_DIM * HID / 4);

  // GEMM1: gamma = x @ We^T + be  -> hid region (f32), 64x128 tile, 512 blocks
  dim3 g1(BATCH / 64, HID / 128);
  gemm_nt<64, 128, 2, 2, 0><<<g1, 256, 0, stream>>>(xb, Web, be, hid, BATCH,
                                                    HID, IN_DIM);

  // ODE: y(1) from gamma, in place; bf16 copy to hb
  ode_kernel<<<2048, 256, 0, stream>>>(hid, hid, hb, BATCH * HID / 4);

  // GEMM2: out = sigmoid(y @ Wd^T + bd), 128x128 tile, 768 blocks
  dim3 g2(BATCH / 128, IN_DIM / 128);
  gemm_nt<128, 128, 2, 2, 1><<<g2, 256, 0, stream>>>(hb, Wdb, bd, out, BATCH,
                                                     IN_DIM, HID);
}

// Round 3
// 126.039 us; speedup vs baseline: 1.3059x; 1.1309x over previous
//
#include <hip/hip_runtime.h>
#include <hip/hip_bf16.h>

#define BATCH 4096
#define IN_DIM 3072
#define HID 1024
#define NSTEP 8

typedef __attribute__((ext_vector_type(8))) short short8;
typedef __attribute__((ext_vector_type(4))) float f32x4;
typedef __attribute__((ext_vector_type(4))) unsigned short ushort4v;

__device__ __forceinline__ void gload_lds16(const void* g, void* lds) {
  __builtin_amdgcn_global_load_lds(
      (const __attribute__((address_space(1))) void*)g,
      (__attribute__((address_space(3))) void*)lds, 16, 0, 0);
}

__device__ __forceinline__ unsigned short f32_to_bf16(float f) {
  unsigned int u = __builtin_bit_cast(unsigned int, f);
  unsigned int r = u + 0x7fffu + ((u >> 16) & 1u);
  return (unsigned short)(r >> 16);
}

// fused f32 -> bf16 conversion of x, We, Wd (one launch)
__global__ void cvt3_kernel(const float* __restrict__ a,
                            const float* __restrict__ b,
                            const float* __restrict__ c,
                            unsigned short* __restrict__ da,
                            unsigned short* __restrict__ db,
                            unsigned short* __restrict__ dc, int na, int nb,
                            int nc) {
  const int total = na + nb + nc;
  const int stride = gridDim.x * blockDim.x;
  for (int i = blockIdx.x * blockDim.x + threadIdx.x; i < total; i += stride) {
    const float* s;
    unsigned short* d;
    int j = i;
    if (j < na) {
      s = a; d = da;
    } else if (j < na + nb) {
      s = b; d = db; j -= na;
    } else {
      s = c; d = dc; j -= na + nb;
    }
    const float4 v = reinterpret_cast<const float4*>(s)[j];
    ushort4v o;
    o.x = f32_to_bf16(v.x);
    o.y = f32_to_bf16(v.y);
    o.z = f32_to_bf16(v.z);
    o.w = f32_to_bf16(v.w);
    reinterpret_cast<ushort4v*>(d)[j] = o;
  }
}

// RK4 nmODE integrator, elementwise, full occupancy. Reads gamma (f32),
// writes y(1) f32 in-place over gamma, plus bf16 copy for GEMM2.
__global__ __launch_bounds__(256) void ode_kernel(const float* gamma,
                                                  float* hid,
                                                  unsigned short* __restrict__ hb,
                                                  int n4) {
  const float dt = 1.0f / (float)NSTEP;
  const float h2 = 0.5f * dt, hd = dt, h6 = dt / 6.0f;
  int stride = gridDim.x * blockDim.x;
  for (int i = blockIdx.x * blockDim.x + threadIdx.x; i < n4; i += stride) {
    const float4 g4 = reinterpret_cast<const float4*>(gamma)[i];
    float g[4] = {g4.x, g4.y, g4.z, g4.w};
    float y[4] = {0.0f, 0.0f, 0.0f, 0.0f};
#pragma unroll 1
    for (int s = 0; s < NSTEP; ++s) {
      float k1[4], k2[4], k3[4], k4[4];
#pragma unroll
      for (int e = 0; e < 4; ++e) {
        float t = __sinf(y[e] + g[e]);
        k1[e] = t * t - y[e];
      }
#pragma unroll
      for (int e = 0; e < 4; ++e) {
        float yy = fmaf(h2, k1[e], y[e]);
        float t = __sinf(yy + g[e]);
        k2[e] = t * t - yy;
      }
#pragma unroll
      for (int e = 0; e < 4; ++e) {
        float yy = fmaf(h2, k2[e], y[e]);
        float t = __sinf(yy + g[e]);
        k3[e] = t * t - yy;
      }
#pragma unroll
      for (int e = 0; e < 4; ++e) {
        float yy = fmaf(hd, k3[e], y[e]);
        float t = __sinf(yy + g[e]);
        k4[e] = t * t - yy;
      }
#pragma unroll
      for (int e = 0; e < 4; ++e) {
        float ks = k1[e] + 2.0f * (k2[e] + k3[e]) + k4[e];
        y[e] = fmaf(h6, ks, y[e]);
      }
    }
    float4 o4;
    o4.x = y[0]; o4.y = y[1]; o4.z = y[2]; o4.w = y[3];
    reinterpret_cast<float4*>(hid)[i] = o4;
    ushort4v ob;
    ob.x = f32_to_bf16(y[0]);
    ob.y = f32_to_bf16(y[1]);
    ob.z = f32_to_bf16(y[2]);
    ob.w = f32_to_bf16(y[3]);
    reinterpret_cast<ushort4v*>(hb)[i] = ob;
  }
}

// NT GEMM: C[M,N] = A[M,K] * B[N,K]^T + bias.
// BMxBN tile, BK-step, 4 waves (WM x WN), double-buffered LDS.
// XOR-swizzled LDS (rule #21: linear gload_lds dest + inverse-swizzled global
// source + swizzled ds_read): 16B granule g of row r stored at slot g^(r&7).
// EPI=0: plain f32 out.  EPI=1: sigmoid f32 out.
template <int BM, int BN, int BK, int WM, int WN, int EPI>
__global__ __launch_bounds__(256) void gemm_nt(
    const unsigned short* __restrict__ A, const unsigned short* __restrict__ B,
    const float* __restrict__ bias, float* __restrict__ Cout, int M, int N,
    int K) {
  constexpr int WTM = BM / WM;        // wave tile rows
  constexpr int WTN = BN / WN;        // wave tile cols
  constexpr int AM = WTM / 16;        // acc frags m
  constexpr int AN = WTN / 16;        // acc frags n
  constexpr int KK = BK / 32;         // mfma k-steps per tile
  constexpr int KG = BK / 8;          // 16B granules per row
  constexpr int UA = BM * KG;         // short8 units in A tile
  constexpr int UB = BN * KG;         // short8 units in B tile
  constexpr int NU = (UA + UB) / 256; // loads per thread per tile

  __shared__ unsigned short As[2][BM * BK];
  __shared__ unsigned short Bs[2][BN * BK];

  const int tid = threadIdx.x;
  const int wave = tid >> 6;
  const int lane = tid & 63;
  const int wrow = wave / WN, wcol = wave % WN;
  const int bm = blockIdx.x, bn = blockIdx.y;

  const unsigned short* Ablk = A + (size_t)bm * BM * K;
  const unsigned short* Bblk = B + (size_t)bn * BN * K;

  auto STAGE = [&](int buf, int k0) {
#pragma unroll
    for (int i = 0; i < NU; ++i) {
      const int u = i * 256 + tid;             // per-lane unit
      const int ubase = i * 256 + wave * 64;   // wave-uniform LDS base unit
      if (ubase < UA) {
        const int row = u / KG;
        const int g = (u % KG) ^ (row & 7);    // inverse-swizzled source granule
        gload_lds16(Ablk + (size_t)row * K + k0 + g * 8,
                    (void*)&As[buf][ubase * 8]);
      } else {
        const int ub = u - UA;
        const int row = ub / KG;
        const int g = (ub % KG) ^ (row & 7);
        gload_lds16(Bblk + (size_t)row * K + k0 + g * 8,
                    (void*)&Bs[buf][(ubase - UA) * 8]);
      }
    }
  };

  f32x4 acc[AM][AN] = {};
  const int fr = lane & 15;
  const int hi = lane >> 4;

  const int nt = K / BK;
  STAGE(0, 0);
  for (int t = 0; t < nt; ++t) {
    const int buf = t & 1;
    __syncthreads();  // implicit vmcnt(0): staged tile t resident
    if (t + 1 < nt) STAGE(buf ^ 1, (t + 1) * BK);

    short8 af[AM][KK], bfr[AN][KK];
#pragma unroll
    for (int m = 0; m < AM; ++m) {
      const int row = wrow * WTM + m * 16 + fr;
#pragma unroll
      for (int kk = 0; kk < KK; ++kk) {
        const int g = (kk * 4 + hi) ^ (fr & 7);  // swizzled read granule
        af[m][kk] =
            *reinterpret_cast<const short8*>(&As[buf][row * BK + g * 8]);
      }
    }
#pragma unroll
    for (int n = 0; n < AN; ++n) {
      const int row = wcol * WTN + n * 16 + fr;
#pragma unroll
      for (int kk = 0; kk < KK; ++kk) {
        const int g = (kk * 4 + hi) ^ (fr & 7);
        bfr[n][kk] =
            *reinterpret_cast<const short8*>(&Bs[buf][row * BK + g * 8]);
      }
    }
#pragma unroll
    for (int kk = 0; kk < KK; ++kk)
#pragma unroll
      for (int m = 0; m < AM; ++m)
#pragma unroll
        for (int n = 0; n < AN; ++n)
          acc[m][n] = __builtin_amdgcn_mfma_f32_16x16x32_bf16(
              af[m][kk], bfr[n][kk], acc[m][n], 0, 0, 0);
  }

  // epilogue: C/D layout col=lane&15, row=(lane>>4)*4+reg (m89-verified)
  const int rquad = hi * 4;
  const int colbase = bn * BN + wcol * WTN + fr;
  const int rowbase = bm * BM + wrow * WTM + rquad;

#pragma unroll
  for (int n = 0; n < AN; ++n) {
    const float bv = bias[colbase + n * 16];
#pragma unroll
    for (int m = 0; m < AM; ++m)
#pragma unroll
      for (int r = 0; r < 4; ++r) {
        float v = acc[m][n][r] + bv;
        if (EPI == 1) v = 1.0f / (1.0f + __expf(-v));
        size_t idx = (size_t)(rowbase + m * 16 + r) * N + (colbase + n * 16);
        Cout[idx] = v;
      }
  }
}

extern "C" void kernel_launch(void* const* d_in, const int* in_sizes, int n_in,
                              void* d_out, int out_size, void* d_ws,
                              size_t ws_size, hipStream_t stream) {
  const float* x = (const float*)d_in[0];
  const float* We = (const float*)d_in[1];
  const float* be = (const float*)d_in[2];
  const float* Wd = (const float*)d_in[3];
  const float* bd = (const float*)d_in[4];

  float* out = (float*)d_out;                   // [4096,3072]
  float* hid = out + (size_t)BATCH * IN_DIM;    // [4096,1024] (gamma, then y)

  unsigned short* xb = (unsigned short*)d_ws;          // bf16 x   [4096,3072]
  unsigned short* Web = xb + (size_t)BATCH * IN_DIM;   // bf16 We  [1024,3072]
  unsigned short* Wdb = Web + (size_t)HID * IN_DIM;    // bf16 Wd  [3072,1024]
  unsigned short* hb = Wdb + (size_t)IN_DIM * HID;     // bf16 hid [4096,1024]

  cvt3_kernel<<<2048, 256, 0, stream>>>(
      x, We, Wd, xb, Web, Wdb, BATCH * IN_DIM / 4, HID * IN_DIM / 4,
      IN_DIM * HID / 4);

  // GEMM1: gamma = x @ We^T + be -> hid region (f32). 64x64, BK=64, 1024 blks
  dim3 g1(BATCH / 64, HID / 64);
  gemm_nt<64, 64, 64, 2, 2, 0><<<g1, 256, 0, stream>>>(xb, Web, be, hid, BATCH,
                                                       HID, IN_DIM);

  // ODE: y(1) from gamma, in place; bf16 copy to hb
  ode_kernel<<<2048, 256, 0, stream>>>(hid, hid, hb, BATCH * HID / 4);

  // GEMM2: out = sigmoid(y @ Wd^T + bd). 64x64, BK=64, 3072 blocks
  dim3 g2(BATCH / 64, IN_DIM / 64);
  gemm_nt<64, 64, 64, 2, 2, 1><<<g2, 256, 0, stream>>>(hb, Wdb, bd, out, BATCH,
                                                       IN_DIM, HID);
}

// Round 4
// 118.926 us; speedup vs baseline: 1.3840x; 1.0598x over previous
//
#include <hip/hip_runtime.h>
#include <hip/hip_bf16.h>

#define BATCH 4096
#define IN_DIM 3072
#define HID 1024
#define NSTEP 8

typedef __attribute__((ext_vector_type(8))) short short8;
typedef __attribute__((ext_vector_type(4))) float f32x4;
typedef __attribute__((ext_vector_type(4))) unsigned short ushort4v;

__device__ __forceinline__ void gload_lds16(const void* g, void* lds) {
  __builtin_amdgcn_global_load_lds(
      (const __attribute__((address_space(1))) void*)g,
      (__attribute__((address_space(3))) void*)lds, 16, 0, 0);
}

__device__ __forceinline__ unsigned short f32_to_bf16(float f) {
  unsigned int u = __builtin_bit_cast(unsigned int, f);
  unsigned int r = u + 0x7fffu + ((u >> 16) & 1u);
  return (unsigned short)(r >> 16);
}

// fused f32 -> bf16 conversion of x, We, Wd (one launch)
__global__ void cvt3_kernel(const float* __restrict__ a,
                            const float* __restrict__ b,
                            const float* __restrict__ c,
                            unsigned short* __restrict__ da,
                            unsigned short* __restrict__ db,
                            unsigned short* __restrict__ dc, int na, int nb,
                            int nc) {
  const int total = na + nb + nc;
  const int stride = gridDim.x * blockDim.x;
  for (int i = blockIdx.x * blockDim.x + threadIdx.x; i < total; i += stride) {
    const float* s;
    unsigned short* d;
    int j = i;
    if (j < na) {
      s = a; d = da;
    } else if (j < na + nb) {
      s = b; d = db; j -= na;
    } else {
      s = c; d = dc; j -= na + nb;
    }
    const float4 v = reinterpret_cast<const float4*>(s)[j];
    ushort4v o;
    o.x = f32_to_bf16(v.x);
    o.y = f32_to_bf16(v.y);
    o.z = f32_to_bf16(v.z);
    o.w = f32_to_bf16(v.w);
    reinterpret_cast<ushort4v*>(d)[j] = o;
  }
}

// Split-K reduce (p0+p1+bias) fused with RK4 nmODE integrator.
// Writes y(1) f32 to hid and bf16 to hb.
__global__ __launch_bounds__(256) void ode_kernel(
    const float* __restrict__ p0, const float* __restrict__ p1,
    const float* __restrict__ be, float* __restrict__ hid,
    unsigned short* __restrict__ hb, int n4) {
  const float dt = 1.0f / (float)NSTEP;
  const float h2 = 0.5f * dt, hd = dt, h6 = dt / 6.0f;
  int stride = gridDim.x * blockDim.x;
  for (int i = blockIdx.x * blockDim.x + threadIdx.x; i < n4; i += stride) {
    const float4 a4 = reinterpret_cast<const float4*>(p0)[i];
    const float4 b4 = reinterpret_cast<const float4*>(p1)[i];
    const float4 e4 = reinterpret_cast<const float4*>(be)[i & (HID / 4 - 1)];
    float g[4] = {a4.x + b4.x + e4.x, a4.y + b4.y + e4.y,
                  a4.z + b4.z + e4.z, a4.w + b4.w + e4.w};
    float y[4] = {0.0f, 0.0f, 0.0f, 0.0f};
#pragma unroll 1
    for (int s = 0; s < NSTEP; ++s) {
      float k1[4], k2[4], k3[4], k4[4];
#pragma unroll
      for (int e = 0; e < 4; ++e) {
        float t = __sinf(y[e] + g[e]);
        k1[e] = t * t - y[e];
      }
#pragma unroll
      for (int e = 0; e < 4; ++e) {
        float yy = fmaf(h2, k1[e], y[e]);
        float t = __sinf(yy + g[e]);
        k2[e] = t * t - yy;
      }
#pragma unroll
      for (int e = 0; e < 4; ++e) {
        float yy = fmaf(h2, k2[e], y[e]);
        float t = __sinf(yy + g[e]);
        k3[e] = t * t - yy;
      }
#pragma unroll
      for (int e = 0; e < 4; ++e) {
        float yy = fmaf(hd, k3[e], y[e]);
        float t = __sinf(yy + g[e]);
        k4[e] = t * t - yy;
      }
#pragma unroll
      for (int e = 0; e < 4; ++e) {
        float ks = k1[e] + 2.0f * (k2[e] + k3[e]) + k4[e];
        y[e] = fmaf(h6, ks, y[e]);
      }
    }
    float4 o4;
    o4.x = y[0]; o4.y = y[1]; o4.z = y[2]; o4.w = y[3];
    reinterpret_cast<float4*>(hid)[i] = o4;
    ushort4v ob;
    ob.x = f32_to_bf16(y[0]);
    ob.y = f32_to_bf16(y[1]);
    ob.z = f32_to_bf16(y[2]);
    ob.w = f32_to_bf16(y[3]);
    reinterpret_cast<ushort4v*>(hb)[i] = ob;
  }
}

// NT GEMM: C[M,N] = A[M,K] * B[N,K]^T (+ bias).
// BMxBN tile, BK-step, 4 waves (2x2), double-buffered LDS, XOR-swizzled
// (rule #21: linear gload_lds dest + inverse-swizzled global source +
// swizzled ds_read). 1-D grid with chunked XCD swizzle; NSK-way split-K
// (partials at Cout + sk*M*Nout).
// EPI=0: raw f32 store (no bias). EPI=1: bias + sigmoid.
template <int BM, int BN, int BK, int NSK, int EPI>
__global__ __launch_bounds__(256) void gemm_nt(
    const unsigned short* __restrict__ A, const unsigned short* __restrict__ B,
    const float* __restrict__ bias, float* __restrict__ Cout, int Kstride,
    int Nout, int nbm, int nbn, int M) {
  constexpr int WTM = BM / 2;         // wave tile rows
  constexpr int WTN = BN / 2;         // wave tile cols
  constexpr int AM = WTM / 16;        // acc frags m
  constexpr int AN = WTN / 16;        // acc frags n
  constexpr int KK = BK / 32;         // mfma k-steps per tile
  constexpr int KG = BK / 8;          // 16B granules per row
  constexpr int UA = BM * KG;         // short8 units in A tile
  constexpr int UB = BN * KG;         // short8 units in B tile
  constexpr int NU = (UA + UB) / 256; // loads per thread per tile

  __shared__ unsigned short As[2][BM * BK];
  __shared__ unsigned short Bs[2][BN * BK];

  const int tid = threadIdx.x;
  const int wave = tid >> 6;
  const int lane = tid & 63;
  const int wrow = wave >> 1, wcol = wave & 1;

  // chunked XCD swizzle (grid divisible by 8), bn-fastest decode
  const int nwg = gridDim.x;
  const int swz = (blockIdx.x & 7) * (nwg >> 3) + (blockIdx.x >> 3);
  const int bn = swz % nbn;
  const int tmp = swz / nbn;
  const int bm = tmp % nbm;
  const int sk = tmp / nbm;

  const int Klen = Kstride / NSK;
  const unsigned short* Ablk = A + (size_t)bm * BM * Kstride + sk * Klen;
  const unsigned short* Bblk = B + (size_t)bn * BN * Kstride + sk * Klen;

  auto STAGE = [&](int buf, int k0) {
#pragma unroll
    for (int i = 0; i < NU; ++i) {
      const int u = i * 256 + tid;             // per-lane unit
      const int ubase = i * 256 + wave * 64;   // wave-uniform LDS base unit
      if (ubase < UA) {
        const int row = u / KG;
        const int g = (u % KG) ^ (row & 7);    // inverse-swizzled source
        gload_lds16(Ablk + (size_t)row * Kstride + k0 + g * 8,
                    (void*)&As[buf][ubase * 8]);
      } else {
        const int ub = u - UA;
        const int row = ub / KG;
        const int g = (ub % KG) ^ (row & 7);
        gload_lds16(Bblk + (size_t)row * Kstride + k0 + g * 8,
                    (void*)&Bs[buf][(ubase - UA) * 8]);
      }
    }
  };

  f32x4 acc[AM][AN] = {};
  const int fr = lane & 15;
  const int hi = lane >> 4;

  const int nt = Klen / BK;
  STAGE(0, 0);
  for (int t = 0; t < nt; ++t) {
    const int buf = t & 1;
    __syncthreads();  // implicit vmcnt(0): staged tile t resident
    if (t + 1 < nt) STAGE(buf ^ 1, (t + 1) * BK);

    short8 af[AM][KK], bfr[AN][KK];
#pragma unroll
    for (int m = 0; m < AM; ++m) {
      const int row = wrow * WTM + m * 16 + fr;
#pragma unroll
      for (int kk = 0; kk < KK; ++kk) {
        const int g = (kk * 4 + hi) ^ (fr & 7);  // swizzled read granule
        af[m][kk] =
            *reinterpret_cast<const short8*>(&As[buf][row * BK + g * 8]);
      }
    }
#pragma unroll
    for (int n = 0; n < AN; ++n) {
      const int row = wcol * WTN + n * 16 + fr;
#pragma unroll
      for (int kk = 0; kk < KK; ++kk) {
        const int g = (kk * 4 + hi) ^ (fr & 7);
        bfr[n][kk] =
            *reinterpret_cast<const short8*>(&Bs[buf][row * BK + g * 8]);
      }
    }
#pragma unroll
    for (int kk = 0; kk < KK; ++kk)
#pragma unroll
      for (int m = 0; m < AM; ++m)
#pragma unroll
        for (int n = 0; n < AN; ++n)
          acc[m][n] = __builtin_amdgcn_mfma_f32_16x16x32_bf16(
              af[m][kk], bfr[n][kk], acc[m][n], 0, 0, 0);
  }

  // epilogue: C/D layout col=lane&15, row=(lane>>4)*4+reg (m89-verified)
  const int rquad = hi * 4;
  const int colbase = bn * BN + wcol * WTN + fr;
  const int rowbase = bm * BM + wrow * WTM + rquad;
  float* Cblk = Cout + (size_t)sk * M * Nout;

#pragma unroll
  for (int n = 0; n < AN; ++n) {
    const float bv = (EPI == 1) ? bias[colbase + n * 16] : 0.0f;
#pragma unroll
    for (int m = 0; m < AM; ++m)
#pragma unroll
      for (int r = 0; r < 4; ++r) {
        float v = acc[m][n][r] + bv;
        if (EPI == 1) v = 1.0f / (1.0f + __expf(-v));
        size_t idx = (size_t)(rowbase + m * 16 + r) * Nout + (colbase + n * 16);
        Cblk[idx] = v;
      }
  }
}

extern "C" void kernel_launch(void* const* d_in, const int* in_sizes, int n_in,
                              void* d_out, int out_size, void* d_ws,
                              size_t ws_size, hipStream_t stream) {
  const float* x = (const float*)d_in[0];
  const float* We = (const float*)d_in[1];
  const float* be = (const float*)d_in[2];
  const float* Wd = (const float*)d_in[3];
  const float* bd = (const float*)d_in[4];

  float* out = (float*)d_out;                   // [4096,3072]
  float* hid = out + (size_t)BATCH * IN_DIM;    // [4096,1024]
  // split-K partials live in the (not-yet-written) out region: 33.6MB <= 50MB
  float* part = out;

  unsigned short* xb = (unsigned short*)d_ws;          // bf16 x   [4096,3072]
  unsigned short* Web = xb + (size_t)BATCH * IN_DIM;   // bf16 We  [1024,3072]
  unsigned short* Wdb = Web + (size_t)HID * IN_DIM;    // bf16 Wd  [3072,1024]
  unsigned short* hb = Wdb + (size_t)IN_DIM * HID;     // bf16 hid [4096,1024]

  cvt3_kernel<<<2048, 256, 0, stream>>>(
      x, We, Wd, xb, Web, Wdb, BATCH * IN_DIM / 4, HID * IN_DIM / 4,
      IN_DIM * HID / 4);

  // GEMM1: partials of x @ We^T -> part[2][4096][1024]. 128x128, BK=64,
  // split-K=2, 512 blocks (2/CU)
  gemm_nt<128, 128, 64, 2, 0><<<512, 256, 0, stream>>>(
      xb, Web, nullptr, part, IN_DIM, HID, BATCH / 128, HID / 128, BATCH);

  // ODE: gamma = p0+p1+be, integrate; y -> hid (f32) + hb (bf16)
  ode_kernel<<<2048, 256, 0, stream>>>(part, part + (size_t)BATCH * HID, be,
                                       hid, hb, BATCH * HID / 4);

  // GEMM2: out = sigmoid(y @ Wd^T + bd). 128x128, BK=64, 768 blocks
  gemm_nt<128, 128, 64, 1, 1><<<768, 256, 0, stream>>>(
      hb, Wdb, bd, out, HID, IN_DIM, BATCH / 128, IN_DIM / 128, BATCH);
}